// Round 8
// baseline (287.381 us; speedup 1.0000x reference)
//
#include <hip/hip_runtime.h>
#include <limits.h>

// CCL 8-connectivity on 4096x4096 binary image (prob > 0.5).
// Output: int32 labels, label = (min linear index in component) + 1, bg = 0.
//
// Local phase: BKE 2x2-block union-find in LDS on PIXEL KEYS over 128x128
// tiles (512-thread blocks => full 32-wave/CU occupancy for latency hiding).
// Border phase: block-level unites across tile boundaries, ONE THREAD PER
// LINK-SLOT (3 per 2-pixel segment; same link set as R7 => same correctness,
// 3x parallelism, 1/3 serial chain depth per thread).
// Final: fused resolve+convert to d_out.

constexpr int HH = 4096;
constexpr int WW = 4096;
constexpr int NPIX = HH * WW;
constexpr int TILE = 128;
constexpr int BDIM = TILE / 2;        // 64 blocks per tile dim
constexpr int NBLK = BDIM * BDIM;     // 4096
constexpr int NBOUND = HH / TILE - 1; // 31 boundaries per family
constexpr int NSEG = WW / 2;          // 2048 segments per boundary
constexpr int LINKS_PER_FAM = NBOUND * NSEG * 3;   // 190464

// ---------------------------------------------------- global union-find ---
__device__ __forceinline__ int find_root_g(int* P, int x) {
    while (true) {
        int p = P[x];
        if (p == x) return x;
        int gp = P[p];
        if (gp == p) return p;
        atomicMin(&P[x], gp);   // path halving (monotone => race-safe)
        x = gp;
    }
}

__device__ __forceinline__ void unite_g(int* P, int a, int b) {
    while (true) {
        a = find_root_g(P, a);
        b = find_root_g(P, b);
        if (a == b) return;
        if (a > b) { int t = a; a = b; b = t; }
        int old = atomicMin(&P[b], a);
        if (old == b) return;
        b = old;
    }
}

// ------------------------------------------- LDS union-find on pixel keys -
// key = local pixel index lr*128+lc (0..16383). Block of a key:
__device__ __forceinline__ int lkey2b(int k) {
    return ((k >> 8) << 6) | ((k & 127) >> 1);   // (lr>>1)*64 + (lc>>1)
}

// stored values are always canonical keys (block-min fg pixel); atomicMin
// over pixel-raster order => monotone, lock-free safe.
__device__ __forceinline__ int find_l(int* par, int bk) {
    while (true) {
        int xb = lkey2b(bk);
        int p = par[xb];
        if (p == bk) return bk;          // root
        int pb = lkey2b(p);
        int gp = par[pb];
        if (gp == p) return p;           // parent is root
        atomicMin(&par[xb], gp);         // path halving
        bk = gp;
    }
}

__device__ __forceinline__ void unite_l(int* par, int ka, int kb) {
    while (true) {
        ka = find_l(par, ka);
        kb = find_l(par, kb);
        if (ka == kb) return;
        if (ka > kb) { int t = ka; ka = kb; kb = t; }
        int old = atomicMin(&par[lkey2b(kb)], ka);
        if (old == kb) return;
        kb = old;
    }
}

// block's own key: min fg pixel (bit0=+0, bit1=+1, bit2=+128, bit3=+129)
__device__ __forceinline__ int bkey(int b, int m) {
    int base = ((b >> 6) << 8) + ((b & 63) << 1);   // (2i)*128 + 2j
    int off = (m & 1) ? 0 : (m & 2) ? 1 : (m & 4) ? 128 : 129;
    return base + off;
}

// ------------------------------------------- local (per-tile) BKE CCL -----
// Block masks: bit0=(r,c) bit1=(r,c+1) bit2=(r+1,c) bit3=(r+1,c+1).
// Left col=0x5, right col=0xA, top row=0x3, bottom row=0xC.
__global__ __launch_bounds__(512) void ccl_local_bke(const float* __restrict__ prob,
                                                     int* __restrict__ P) {
    __shared__ int bmask[NBLK];
    __shared__ int par[NBLK];
    const int tile_c = blockIdx.x * TILE;
    const int tile_r = blockIdx.y * TILE;
    const int tid = threadIdx.x;

    int nib[8];
    #pragma unroll
    for (int k = 0; k < 8; ++k) {
        int b = tid + 512 * k;
        int i = b >> 6, j = b & 63;
        const float* rp = prob + (size_t)(tile_r + 2 * i) * WW + tile_c + 2 * j;
        float2 t = *reinterpret_cast<const float2*>(rp);
        float2 bo = *reinterpret_cast<const float2*>(rp + WW);
        int m = (t.x > 0.5f ? 1 : 0) | (t.y > 0.5f ? 2 : 0) |
                (bo.x > 0.5f ? 4 : 0) | (bo.y > 0.5f ? 8 : 0);
        nib[k] = m;
        bmask[b] = m;
        par[b] = m ? bkey(b, m) : -1;
    }
    __syncthreads();

    #pragma unroll
    for (int k = 0; k < 8; ++k) {
        int m = nib[k];
        if (!m) continue;
        int b = tid + 512 * k;
        int i = b >> 6, j = b & 63;
        int mk = bkey(b, m);
        if (j > 0) {
            int wm = bmask[b - 1];
            if ((m & 0x5) && (wm & 0xA)) unite_l(par, mk, bkey(b - 1, wm));
        }
        if (i > 0) {
            int nm = bmask[b - BDIM];
            if ((m & 0x3) && (nm & 0xC)) unite_l(par, mk, bkey(b - BDIM, nm));
            if (j > 0) {
                int nwm = bmask[b - BDIM - 1];
                if ((m & 0x1) && (nwm & 0x8)) unite_l(par, mk, bkey(b - BDIM - 1, nwm));
            }
            if (j < BDIM - 1) {
                int nem = bmask[b - BDIM + 1];
                if ((m & 0x2) && (nem & 0x4)) unite_l(par, mk, bkey(b - BDIM + 1, nem));
            }
        }
    }
    __syncthreads();

    #pragma unroll
    for (int k = 0; k < 8; ++k) {
        int b = tid + 512 * k;
        int i = b >> 6, j = b & 63;
        int gr = tile_r + 2 * i, gc = tile_c + 2 * j;
        int m = nib[k];
        int2 top = make_int2(-1, -1), bot = make_int2(-1, -1);
        if (m) {
            int x = bkey(b, m);
            while (true) {               // read-only chase (par is stable now)
                int p = par[lkey2b(x)];
                if (p == x) break;
                x = p;
            }
            int g = (tile_r + (x >> 7)) * WW + tile_c + (x & 127);
            top.x = (m & 1) ? g : -1;
            top.y = (m & 2) ? g : -1;
            bot.x = (m & 4) ? g : -1;
            bot.y = (m & 8) ? g : -1;
        }
        *reinterpret_cast<int2*>(P + (size_t)gr * WW + gc) = top;
        *reinterpret_cast<int2*>(P + (size_t)(gr + 1) * WW + gc) = bot;
    }
}

// ----------------------- block-level cross-tile border unites -------------
// One thread per LINK SLOT. Link set identical to R7 (proven complete):
// horizontal boundary (row r), segment {c0,c0+1}:
//   slot0: column unite (any fg below) x (any fg above)
//   slot1: (r,c0)   -- (r-1,c0-1)  outer-left diagonal
//   slot2: (r,c0+1) -- (r-1,c0+2)  outer-right diagonal
// vertical boundary (col c), segment {r0,r0+1}: symmetric.
__global__ void ccl_border(int* __restrict__ P) {
    int idx = blockIdx.x * 256 + threadIdx.x;
    if (idx >= LINKS_PER_FAM) return;
    int link = idx / (NBOUND * NSEG);          // 0,1,2 (slow index)
    int rem  = idx - link * (NBOUND * NSEG);
    int bidx = rem >> 11;                      // boundary index
    int t    = rem & (NSEG - 1);               // segment index
    if (blockIdx.y == 0) {
        int r = (bidx + 1) * TILE;
        int c0 = 2 * t;
        if (link == 0) {
            int2 d = *reinterpret_cast<const int2*>(P + (size_t)r * WW + c0);
            int2 u = *reinterpret_cast<const int2*>(P + (size_t)(r - 1) * WW + c0);
            bool d0 = d.x >= 0, d1 = d.y >= 0;
            bool u0 = u.x >= 0, u1 = u.y >= 0;
            if ((d0 | d1) && (u0 | u1)) {
                int pd = d0 ? r * WW + c0 : r * WW + c0 + 1;
                int pu = u0 ? (r - 1) * WW + c0 : (r - 1) * WW + c0 + 1;
                unite_g(P, pd, pu);
            }
        } else if (link == 1) {
            if (c0 > 0 && P[(size_t)r * WW + c0] >= 0 &&
                P[(size_t)(r - 1) * WW + c0 - 1] >= 0)
                unite_g(P, r * WW + c0, (r - 1) * WW + c0 - 1);
        } else {
            if (c0 + 2 < WW && P[(size_t)r * WW + c0 + 1] >= 0 &&
                P[(size_t)(r - 1) * WW + c0 + 2] >= 0)
                unite_g(P, r * WW + c0 + 1, (r - 1) * WW + c0 + 2);
        }
    } else {
        int c = (bidx + 1) * TILE;
        int r0 = 2 * t;
        if (link == 0) {
            bool e0 = P[(size_t)r0 * WW + c] >= 0;
            bool e1 = P[(size_t)(r0 + 1) * WW + c] >= 0;
            bool w0 = P[(size_t)r0 * WW + c - 1] >= 0;
            bool w1 = P[(size_t)(r0 + 1) * WW + c - 1] >= 0;
            if ((e0 | e1) && (w0 | w1)) {
                int pe = e0 ? r0 * WW + c : (r0 + 1) * WW + c;
                int pw = w0 ? r0 * WW + c - 1 : (r0 + 1) * WW + c - 1;
                unite_g(P, pe, pw);
            }
        } else if (link == 1) {
            if (r0 > 0 && P[(size_t)r0 * WW + c] >= 0 &&
                P[(size_t)(r0 - 1) * WW + c - 1] >= 0)
                unite_g(P, r0 * WW + c, (r0 - 1) * WW + c - 1);
        } else {
            if (r0 + 2 < HH && P[(size_t)(r0 + 1) * WW + c] >= 0 &&
                P[(size_t)(r0 + 2) * WW + c - 1] >= 0)
                unite_g(P, (r0 + 1) * WW + c, (r0 + 2) * WW + c - 1);
        }
    }
}

// ------------------------------------------ resolve + convert (to d_out) --
__device__ __forceinline__ int resolve_memo(const int* __restrict__ P, int x,
                                            int& ci, int& co) {
    if (x < 0) return 0;
    if (x == ci) return co;
    int r = x;
    while (true) { int p = P[r]; if (p == r) break; r = p; }
    ci = x; co = r + 1;
    return co;
}

__global__ void ccl_final4(const int* __restrict__ P, int* __restrict__ out) {
    int i = (blockIdx.x * blockDim.x + threadIdx.x) * 4;
    int4 v = *reinterpret_cast<const int4*>(P + i);
    int ci = -2, co = 0;
    int4 o;
    o.x = resolve_memo(P, v.x, ci, co);
    o.y = resolve_memo(P, v.y, ci, co);
    o.z = resolve_memo(P, v.z, ci, co);
    o.w = resolve_memo(P, v.w, ci, co);
    *reinterpret_cast<int4*>(out + i) = o;
}

// ---------------------------- fallback path (P aliases d_out, no ws) ------
__global__ void ccl_compress(int* __restrict__ P) {
    int i = blockIdx.x * blockDim.x + threadIdx.x;
    int x = P[i];
    if (x < 0) return;
    while (true) { int p = P[x]; if (p == x) break; x = p; }
    P[i] = x;
}

__global__ void ccl_convert(int* __restrict__ P) {
    int i = (blockIdx.x * blockDim.x + threadIdx.x) * 4;
    int4 v = *reinterpret_cast<const int4*>(P + i);
    v.x = (v.x < 0) ? 0 : v.x + 1;
    v.y = (v.y < 0) ? 0 : v.y + 1;
    v.z = (v.z < 0) ? 0 : v.z + 1;
    v.w = (v.w < 0) ? 0 : v.w + 1;
    *reinterpret_cast<int4*>(P + i) = v;
}

// ---------------------------------------------------------------- launch --
extern "C" void kernel_launch(void* const* d_in, const int* in_sizes, int n_in,
                              void* d_out, int out_size, void* d_ws, size_t ws_size,
                              hipStream_t stream) {
    const float* prob = (const float*)d_in[0];
    const bool have_ws = ws_size >= (size_t)NPIX * sizeof(int);
    int* P = have_ws ? (int*)d_ws : (int*)d_out;

    ccl_local_bke<<<dim3(WW / TILE, HH / TILE), dim3(512), 0, stream>>>(prob, P);

    // one thread per link slot: 3 * 31 * 2048 per family, 2 families
    ccl_border<<<dim3((LINKS_PER_FAM + 255) / 256, 2), dim3(256), 0, stream>>>(P);

    if (have_ws) {
        ccl_final4<<<dim3(NPIX / 4 / 256), dim3(256), 0, stream>>>(P, (int*)d_out);
    } else {
        ccl_compress<<<dim3(NPIX / 256), dim3(256), 0, stream>>>(P);
        ccl_convert<<<dim3(NPIX / 4 / 256), dim3(256), 0, stream>>>(P);
    }
}

// Round 9
// 241.095 us; speedup vs baseline: 1.1920x; 1.1920x over previous
//
#include <hip/hip_runtime.h>
#include <limits.h>

// CCL 8-connectivity on 4096x4096 binary image (prob > 0.5).
// Output: int32 labels, label = (min linear index in component) + 1, bg = 0.
//
// Local: BKE 2x2-block union-find in LDS on PIXEL KEYS over 128x128 tiles.
// Border: serial-per-thread unites with RUN-START DEDUP. Dedup coverage uses
// ONLY (a) local-pass intra-tile links (unconditional) and (b) this same
// family's unites at smaller in-tile offsets (well-founded induction) — no
// cross-family reliance (the R4 corner bug). At in-tile offsets 0/127 all
// links are unconditional. Unites start from parent values (1 hop saved).
// Final: fused resolve+convert to d_out.

constexpr int HH = 4096;
constexpr int WW = 4096;
constexpr int NPIX = HH * WW;
constexpr int TILE = 128;
constexpr int BDIM = TILE / 2;        // 64 blocks per tile dim
constexpr int NBLK = BDIM * BDIM;     // 4096
constexpr int NBOUND = HH / TILE - 1; // 31 boundaries per family
constexpr int SEGW = 4;               // columns/rows handled per thread
constexpr int NSEG4 = WW / SEGW;      // 1024 segments per boundary
constexpr int THREADS_PER_FAM = NBOUND * NSEG4;   // 31744

// ---------------------------------------------------- global union-find ---
__device__ __forceinline__ int find_root_g(int* P, int x) {
    while (true) {
        int p = P[x];
        if (p == x) return x;
        int gp = P[p];
        if (gp == p) return p;
        atomicMin(&P[x], gp);   // path halving (monotone => race-safe)
        x = gp;
    }
}

__device__ __forceinline__ void unite_g(int* P, int a, int b) {
    while (true) {
        a = find_root_g(P, a);
        b = find_root_g(P, b);
        if (a == b) return;
        if (a > b) { int t = a; a = b; b = t; }
        int old = atomicMin(&P[b], a);
        if (old == b) return;
        b = old;
    }
}

// ------------------------------------------- LDS union-find on pixel keys -
// key = local pixel index lr*128+lc (0..16383). Block of a key:
__device__ __forceinline__ int lkey2b(int k) {
    return ((k >> 8) << 6) | ((k & 127) >> 1);   // (lr>>1)*64 + (lc>>1)
}

__device__ __forceinline__ int find_l(int* par, int bk) {
    while (true) {
        int xb = lkey2b(bk);
        int p = par[xb];
        if (p == bk) return bk;          // root
        int pb = lkey2b(p);
        int gp = par[pb];
        if (gp == p) return p;           // parent is root
        atomicMin(&par[xb], gp);         // path halving
        bk = gp;
    }
}

__device__ __forceinline__ void unite_l(int* par, int ka, int kb) {
    while (true) {
        ka = find_l(par, ka);
        kb = find_l(par, kb);
        if (ka == kb) return;
        if (ka > kb) { int t = ka; ka = kb; kb = t; }
        int old = atomicMin(&par[lkey2b(kb)], ka);
        if (old == kb) return;
        kb = old;
    }
}

// block's own key: min fg pixel (bit0=+0, bit1=+1, bit2=+128, bit3=+129)
__device__ __forceinline__ int bkey(int b, int m) {
    int base = ((b >> 6) << 8) + ((b & 63) << 1);   // (2i)*128 + 2j
    int off = (m & 1) ? 0 : (m & 2) ? 1 : (m & 4) ? 128 : 129;
    return base + off;
}

// ------------------------------------------- local (per-tile) BKE CCL -----
__global__ __launch_bounds__(512) void ccl_local_bke(const float* __restrict__ prob,
                                                     int* __restrict__ P) {
    __shared__ int bmask[NBLK];
    __shared__ int par[NBLK];
    const int tile_c = blockIdx.x * TILE;
    const int tile_r = blockIdx.y * TILE;
    const int tid = threadIdx.x;

    int nib[8];
    #pragma unroll
    for (int k = 0; k < 8; ++k) {
        int b = tid + 512 * k;
        int i = b >> 6, j = b & 63;
        const float* rp = prob + (size_t)(tile_r + 2 * i) * WW + tile_c + 2 * j;
        float2 t = *reinterpret_cast<const float2*>(rp);
        float2 bo = *reinterpret_cast<const float2*>(rp + WW);
        int m = (t.x > 0.5f ? 1 : 0) | (t.y > 0.5f ? 2 : 0) |
                (bo.x > 0.5f ? 4 : 0) | (bo.y > 0.5f ? 8 : 0);
        nib[k] = m;
        bmask[b] = m;
        par[b] = m ? bkey(b, m) : -1;
    }
    __syncthreads();

    #pragma unroll
    for (int k = 0; k < 8; ++k) {
        int m = nib[k];
        if (!m) continue;
        int b = tid + 512 * k;
        int i = b >> 6, j = b & 63;
        int mk = bkey(b, m);
        if (j > 0) {
            int wm = bmask[b - 1];
            if ((m & 0x5) && (wm & 0xA)) unite_l(par, mk, bkey(b - 1, wm));
        }
        if (i > 0) {
            int nm = bmask[b - BDIM];
            if ((m & 0x3) && (nm & 0xC)) unite_l(par, mk, bkey(b - BDIM, nm));
            if (j > 0) {
                int nwm = bmask[b - BDIM - 1];
                if ((m & 0x1) && (nwm & 0x8)) unite_l(par, mk, bkey(b - BDIM - 1, nwm));
            }
            if (j < BDIM - 1) {
                int nem = bmask[b - BDIM + 1];
                if ((m & 0x2) && (nem & 0x4)) unite_l(par, mk, bkey(b - BDIM + 1, nem));
            }
        }
    }
    __syncthreads();

    #pragma unroll
    for (int k = 0; k < 8; ++k) {
        int b = tid + 512 * k;
        int i = b >> 6, j = b & 63;
        int gr = tile_r + 2 * i, gc = tile_c + 2 * j;
        int m = nib[k];
        int2 top = make_int2(-1, -1), bot = make_int2(-1, -1);
        if (m) {
            int x = bkey(b, m);
            while (true) {               // read-only chase (par is stable now)
                int p = par[lkey2b(x)];
                if (p == x) break;
                x = p;
            }
            int g = (tile_r + (x >> 7)) * WW + tile_c + (x & 127);
            top.x = (m & 1) ? g : -1;
            top.y = (m & 2) ? g : -1;
            bot.x = (m & 4) ? g : -1;
            bot.y = (m & 8) ? g : -1;
        }
        *reinterpret_cast<int2*>(P + (size_t)gr * WW + gc) = top;
        *reinterpret_cast<int2*>(P + (size_t)(gr + 1) * WW + gc) = bot;
    }
}

// ---------------------- dedup'd serial cross-tile border unites -----------
// Horizontal boundary row r, columns c: links N=(D[c],U[c]), NW=(D[c],U[c-1]),
// NE=(D[c],U[c+1]). j=c%128. Perform:
//   N  iff D&U        && (j==0   || !(D[c-1]&U[c-1]))       (run start)
//   NW iff D&U[c-1]   && (j==0   || (!U[c]   & !D[c-1]))
//   NE iff D&U[c+1]   && (j==127 || (!U[c]   & !D[c+1]))
// Coverage of skipped links: intra-tile same-row W-links (local pass) +
// this family's performed unites at smaller in-tile c — well-founded.
// Vertical family symmetric (rows<->cols).
__global__ void ccl_border(int* __restrict__ P) {
    int idx = blockIdx.x * 256 + threadIdx.x;
    if (idx >= THREADS_PER_FAM) return;
    int bidx = idx >> 10;              // boundary index 0..30
    int t    = idx & (NSEG4 - 1);      // segment index
    int dpar[6], upar[6];
    if (blockIdx.y == 0) {
        int r = (bidx + 1) * TILE;
        int c0 = SEGW * t;
        const int* pd = P + (size_t)r * WW;
        const int* pu = pd - WW;
        int4 dv = *reinterpret_cast<const int4*>(pd + c0);
        int4 uv = *reinterpret_cast<const int4*>(pu + c0);
        dpar[0] = (c0 > 0) ? pd[c0 - 1] : -1;
        upar[0] = (c0 > 0) ? pu[c0 - 1] : -1;
        dpar[1] = dv.x; dpar[2] = dv.y; dpar[3] = dv.z; dpar[4] = dv.w;
        upar[1] = uv.x; upar[2] = uv.y; upar[3] = uv.z; upar[4] = uv.w;
        dpar[5] = (c0 + SEGW < WW) ? pd[c0 + SEGW] : -1;
        upar[5] = (c0 + SEGW < WW) ? pu[c0 + SEGW] : -1;
        #pragma unroll
        for (int k = 1; k <= SEGW; ++k) {
            if (dpar[k] < 0) continue;
            int c = c0 + k - 1;
            int j = c & (TILE - 1);
            bool U  = upar[k] >= 0;
            bool Dm = dpar[k - 1] >= 0, Um = upar[k - 1] >= 0;
            bool Dp = dpar[k + 1] >= 0, Up = upar[k + 1] >= 0;
            if (U  && (j == 0        || !(Dm && Um))) unite_g(P, dpar[k], upar[k]);
            if (Um && (j == 0        || (!U && !Dm))) unite_g(P, dpar[k], upar[k - 1]);
            if (Up && (j == TILE - 1 || (!U && !Dp))) unite_g(P, dpar[k], upar[k + 1]);
        }
    } else {
        int c = (bidx + 1) * TILE;
        int r0 = SEGW * t;
        const int* pe = P + c;       // east side (this tile), index by row
        const int* pw = P + c - 1;   // west side
        dpar[0] = (r0 > 0) ? pe[(size_t)(r0 - 1) * WW] : -1;   // E[r0-1]
        upar[0] = (r0 > 0) ? pw[(size_t)(r0 - 1) * WW] : -1;   // W[r0-1]
        #pragma unroll
        for (int k = 1; k <= SEGW; ++k) {
            dpar[k] = pe[(size_t)(r0 + k - 1) * WW];
            upar[k] = pw[(size_t)(r0 + k - 1) * WW];
        }
        dpar[5] = (r0 + SEGW < HH) ? pe[(size_t)(r0 + SEGW) * WW] : -1;
        upar[5] = (r0 + SEGW < HH) ? pw[(size_t)(r0 + SEGW) * WW] : -1;
        #pragma unroll
        for (int k = 1; k <= SEGW; ++k) {
            if (dpar[k] < 0) continue;              // E[r] bg
            int r = r0 + k - 1;
            int i = r & (TILE - 1);
            bool W  = upar[k] >= 0;
            bool Em = dpar[k - 1] >= 0, Wm = upar[k - 1] >= 0;
            bool Ep = dpar[k + 1] >= 0, Wp = upar[k + 1] >= 0;
            if (W  && (i == 0        || !(Em && Wm))) unite_g(P, dpar[k], upar[k]);
            if (Wm && (i == 0        || (!W && !Em))) unite_g(P, dpar[k], upar[k - 1]);
            if (Wp && (i == TILE - 1 || (!W && !Ep))) unite_g(P, dpar[k], upar[k + 1]);
        }
    }
}

// ------------------------------------------ resolve + convert (to d_out) --
__device__ __forceinline__ int resolve_memo(const int* __restrict__ P, int x,
                                            int& ci, int& co) {
    if (x < 0) return 0;
    if (x == ci) return co;
    int r = x;
    while (true) { int p = P[r]; if (p == r) break; r = p; }
    ci = x; co = r + 1;
    return co;
}

__global__ void ccl_final4(const int* __restrict__ P, int* __restrict__ out) {
    int i = (blockIdx.x * blockDim.x + threadIdx.x) * 4;
    int4 v = *reinterpret_cast<const int4*>(P + i);
    int ci = -2, co = 0;
    int4 o;
    o.x = resolve_memo(P, v.x, ci, co);
    o.y = resolve_memo(P, v.y, ci, co);
    o.z = resolve_memo(P, v.z, ci, co);
    o.w = resolve_memo(P, v.w, ci, co);
    *reinterpret_cast<int4*>(out + i) = o;
}

// ---------------------------- fallback path (P aliases d_out, no ws) ------
__global__ void ccl_compress(int* __restrict__ P) {
    int i = blockIdx.x * blockDim.x + threadIdx.x;
    int x = P[i];
    if (x < 0) return;
    while (true) { int p = P[x]; if (p == x) break; x = p; }
    P[i] = x;
}

__global__ void ccl_convert(int* __restrict__ P) {
    int i = (blockIdx.x * blockDim.x + threadIdx.x) * 4;
    int4 v = *reinterpret_cast<const int4*>(P + i);
    v.x = (v.x < 0) ? 0 : v.x + 1;
    v.y = (v.y < 0) ? 0 : v.y + 1;
    v.z = (v.z < 0) ? 0 : v.z + 1;
    v.w = (v.w < 0) ? 0 : v.w + 1;
    *reinterpret_cast<int4*>(P + i) = v;
}

// ---------------------------------------------------------------- launch --
extern "C" void kernel_launch(void* const* d_in, const int* in_sizes, int n_in,
                              void* d_out, int out_size, void* d_ws, size_t ws_size,
                              hipStream_t stream) {
    const float* prob = (const float*)d_in[0];
    const bool have_ws = ws_size >= (size_t)NPIX * sizeof(int);
    int* P = have_ws ? (int*)d_ws : (int*)d_out;

    ccl_local_bke<<<dim3(WW / TILE, HH / TILE), dim3(512), 0, stream>>>(prob, P);

    // dedup'd serial borders: 31 boundaries x 1024 4-wide segments, 2 families
    ccl_border<<<dim3((THREADS_PER_FAM + 255) / 256, 2), dim3(256), 0, stream>>>(P);

    if (have_ws) {
        ccl_final4<<<dim3(NPIX / 4 / 256), dim3(256), 0, stream>>>(P, (int*)d_out);
    } else {
        ccl_compress<<<dim3(NPIX / 256), dim3(256), 0, stream>>>(P);
        ccl_convert<<<dim3(NPIX / 4 / 256), dim3(256), 0, stream>>>(P);
    }
}